// Round 12
// baseline (165.777 us; speedup 1.0000x reference)
//
#include <hip/hip_runtime.h>
#include <cstdint>
#include <cstddef>

constexpr int Bn = 64;     // batch
constexpr int Nn = 1024;   // nodes per graph
constexpr int Dn = 1024;   // input feature dim
constexpr int Cn = 128;    // hidden channels
constexpr int En = 16384;  // edges per graph
constexpr int PAD = 136;   // LDS row stride in bf16 elems

typedef short s16x8 __attribute__((ext_vector_type(8)));   // 8 bf16 = 4 VGPR (MFMA A/B frag)
typedef float f32x4 __attribute__((ext_vector_type(4)));   // MFMA C/D frag

__device__ __forceinline__ uint32_t f2bf(float f) {        // fp32 -> bf16 bits, RNE
    uint32_t u = __float_as_uint(f);
    return (u + 0x7fffu + ((u >> 16) & 1u)) >> 16;
}

// ================= K1: detect | Wc->bf16^T | embedA | zero(indeg,rankcnt) =================
// blocks 0..63 detect; 64..127 wconv; 128..383 embedA; 384 zero.
// meta[1]==1 iff int32 edge data (ws poisoned 0xAA; all writers store 1 -> benign race).
__global__ __launch_bounds__(256) void k_prep(const int* __restrict__ ei32,
                                              const float* __restrict__ Wc,
                                              const float* __restrict__ x,
                                              const float* __restrict__ We,
                                              int* __restrict__ meta,
                                              unsigned short* __restrict__ Wt,
                                              float* __restrict__ pws,
                                              int* __restrict__ indeg,
                                              int* __restrict__ rankcnt) {
    int bid = blockIdx.x, tid = threadIdx.x;
    if (bid < 64) {
        __shared__ int sh;
        if (tid == 0) sh = 0;
        __syncthreads();
        int i = bid * 256 + tid;                 // [0, 16384)
        if (ei32[2 * i + 1]) atomicOr(&sh, 1);
        __syncthreads();
        if (tid == 0 && sh) meta[1] = 1;
    } else if (bid < 128) {
        int i = (bid - 64) * 256 + tid;          // [0, 16384)
        int n = i >> 7, k = i & 127;
        Wt[i] = (unsigned short)f2bf(Wc[k * Cn + n]);
    } else if (bid < 384) {
        __shared__ float sx[256];
        __shared__ float sp[256];
        int bq = bid - 128;
        int b = bq >> 2, q = bq & 3;
        int c = tid & 127, h2 = tid >> 7;
        sx[tid] = x[b * Dn + q * 256 + tid];
        __syncthreads();
        float acc = 0.f;
        int d0 = q * 256 + h2 * 128, dl = h2 * 128;
#pragma unroll 8
        for (int i = 0; i < 128; ++i) acc += sx[dl + i] * We[(d0 + i) * Cn + c];
        sp[h2 * 128 + c] = acc;
        __syncthreads();
        if (h2 == 0) pws[(b * 4 + q) * Cn + c] = sp[c] + sp[128 + c];
    } else {
        int i = tid * 4;
        indeg[i] = 0; indeg[i + 1] = 0; indeg[i + 2] = 0; indeg[i + 3] = 0;
        rankcnt[i] = 0; rankcnt[i + 1] = 0; rankcnt[i + 2] = 0; rankcnt[i + 3] = 0;
    }
}

// ================= K2: hist (0..63) | g (64..127) | levels (128) =================
// levels works on the RAW edge list (no CSR needed): F3={src:dst==0}, F2={src:dst in F3}.
__global__ __launch_bounds__(256) void k_mid(const int* __restrict__ ei32,
                                             const float* __restrict__ pws,
                                             const float* __restrict__ be,
                                             const float* __restrict__ Wc,
                                             int* __restrict__ meta,
                                             int* __restrict__ indeg,
                                             int* __restrict__ L2,
                                             int* __restrict__ L3,
                                             float* __restrict__ g) {
    int bid = blockIdx.x, tid = threadIdx.x;
    if (bid < 64) {
        bool i64 = (meta[1] != 1);
        int e = bid * 256 + tid;
        int dst = ei32[i64 ? 2 * (En + e) : (En + e)] & (Nn - 1);
        atomicAdd(&indeg[dst], 1);
    } else if (bid < 128) {
        __shared__ float se[Cn];
        int b = bid - 64, c = tid & 127;
        float e = pws[(b * 4 + 0) * Cn + c] + pws[(b * 4 + 1) * Cn + c] +
                  pws[(b * 4 + 2) * Cn + c] + pws[(b * 4 + 3) * Cn + c] + be[c];
        se[c] = fmaxf(e, 0.f);                   // both tid-halves write identical value
        __syncthreads();
        float ga = 0.f;
#pragma unroll 8
        for (int k = 0; k < Cn; ++k) ga += se[k] * Wc[k * Cn + c];
        if (tid < 128) g[b * Cn + c] = ga;
    } else {
        __shared__ int f3[Nn];
        __shared__ int f2[Nn];
        __shared__ int c3s, c2s;
        for (int n = tid; n < Nn; n += 256) { f3[n] = 0; f2[n] = 0; }
        if (tid == 0) { c3s = 0; c2s = 0; }
        __syncthreads();
        bool i64 = (meta[1] != 1);
        for (int e = tid; e < En; e += 256) {
            int dst = ei32[i64 ? 2 * (En + e) : (En + e)] & (Nn - 1);
            if (dst == 0) f3[ei32[i64 ? 2 * e : e] & (Nn - 1)] = 1;
        }
        __syncthreads();
        for (int e = tid; e < En; e += 256) {
            int dst = ei32[i64 ? 2 * (En + e) : (En + e)] & (Nn - 1);
            if (f3[dst]) f2[ei32[i64 ? 2 * e : e] & (Nn - 1)] = 1;
        }
        __syncthreads();
        for (int n = tid; n < Nn; n += 256) {
            if (f3[n]) L3[atomicAdd(&c3s, 1)] = n;
            if (f2[n]) L2[atomicAdd(&c2s, 1)] = n;
        }
        __syncthreads();
        if (tid == 0) { meta[2] = c3s; meta[3] = c2s; }
    }
}

// ================= K3: scatter (64 blocks; per-block redundant LDS scan; global rank atomics) =================
// pos = excl_offs[dst] + atomicAdd(&rankcnt[dst],1). Block 0 also publishes offs[] for the convs.
__global__ __launch_bounds__(256) void k_scatter(const int* __restrict__ ei32,
                                                 const int* __restrict__ meta,
                                                 const int* __restrict__ indeg,
                                                 int* __restrict__ rankcnt,
                                                 int* __restrict__ offs,
                                                 int* __restrict__ ssrc,
                                                 float* __restrict__ edeg) {
    __shared__ int sraw[Nn];
    __shared__ int sexcl[Nn];
    __shared__ int sp[256];
    int bid = blockIdx.x, tid = threadIdx.x;
    int i0 = tid * 4;
    int a0 = indeg[i0], a1 = indeg[i0 + 1], a2 = indeg[i0 + 2], a3 = indeg[i0 + 3];
    int s3 = a0 + a1 + a2 + a3;
    sraw[i0] = a0; sraw[i0 + 1] = a1; sraw[i0 + 2] = a2; sraw[i0 + 3] = a3;
    sp[tid] = s3;
    __syncthreads();
    for (int off = 1; off < 256; off <<= 1) {
        int add = (tid >= off) ? sp[tid - off] : 0;
        __syncthreads();
        sp[tid] += add;
        __syncthreads();
    }
    int excl = sp[tid] - s3;
    sexcl[i0] = excl;
    sexcl[i0 + 1] = excl + a0;
    sexcl[i0 + 2] = excl + a0 + a1;
    sexcl[i0 + 3] = excl + a0 + a1 + a2;
    if (bid == 0) {
        offs[i0 + 1] = excl + a0;
        offs[i0 + 2] = excl + a0 + a1;
        offs[i0 + 3] = excl + a0 + a1 + a2;
        offs[i0 + 4] = excl + s3;
        if (tid == 0) offs[0] = 0;
    }
    __syncthreads();
    bool i64 = (meta[1] != 1);
    int e = bid * 256 + tid;
    int src = ei32[i64 ? 2 * e : e] & (Nn - 1);
    int dst = ei32[i64 ? 2 * (En + e) : (En + e)] & (Nn - 1);
    int rank = atomicAdd(&rankcnt[dst], 1);
    int pos = sexcl[dst] + rank;
    if (pos >= 0 && pos < En) { ssrc[pos] = src; edeg[pos] = (float)sraw[src]; }
}

// ================= K4: conv 1+2 fused, frontier-restricted (tile-major: XCD = b%8) =================
__global__ __launch_bounds__(256, 4) void k_conv2L(const float* __restrict__ g,
                                                   float* __restrict__ h2,
                                                   const unsigned short* __restrict__ Wt,
                                                   const float* __restrict__ bc,
                                                   const int* __restrict__ offs,
                                                   const float* __restrict__ edeg,
                                                   const int* __restrict__ L2,
                                                   const int* __restrict__ meta) {
    int bidx = blockIdx.x;
    int tile = bidx >> 6, b = bidx & 63;
    int cnt2 = meta[3];
    if (tile * 32 >= cnt2) return;
    __shared__ unsigned short sSb[32 * PAD];  // 8.7 KB
    __shared__ float sEd[32][64];             // 8 KB
    __shared__ int snode[32], slo[32], scnt[32];
    int tid = threadIdx.x;
    if (tid < 32) {
        int ti = tile * 32 + tid;
        int node = (ti < cnt2) ? L2[ti] : -1;
        snode[tid] = node;
        int lo = (node >= 0) ? offs[node] : 0;
        int hi = (node >= 0) ? offs[node + 1] : 0;
        slo[tid] = lo; scnt[tid] = hi - lo;
    }
    __syncthreads();
    int w = tid >> 6, lane = tid & 63;
#pragma unroll
    for (int r = 0; r < 8; ++r) {
        int row = w * 8 + r;
        int cnt = scnt[row];
        if (lane < cnt && lane < 64) sEd[row][lane] = edeg[slo[row] + lane];
    }
    __syncthreads();

    int c2 = tid & 63;
    float gx = g[b * Cn + 2 * c2], gy = g[b * Cn + 2 * c2 + 1];
    float bx = bc[2 * c2], by = bc[2 * c2 + 1];
#pragma unroll
    for (int t0 = 0; t0 < 8; ++t0) {
        int row = w * 8 + t0;
        int cnt = scnt[row], lo = slo[row];
        float s0 = 0.f, s1 = 0.f;
        int jm = cnt < 64 ? cnt : 64;
        for (int j = 0; j < jm; ++j) {
            float d = sEd[row][j];
            s0 += fmaxf(fmaf(d, gx, bx), 0.f);
            s1 += fmaxf(fmaf(d, gy, by), 0.f);
        }
        for (int j = 64; j < cnt; ++j) {      // rare overflow tail
            float d = edeg[lo + j];
            s0 += fmaxf(fmaf(d, gx, bx), 0.f);
            s1 += fmaxf(fmaf(d, gy, by), 0.f);
        }
        *(uint32_t*)&sSb[row * PAD + 2 * c2] = f2bf(s0) | (f2bf(s1) << 16);
    }

    int m = lane & 15, quad = lane >> 4;
    s16x8 bf0[4], bf1[4];
#pragma unroll
    for (int ks = 0; ks < 4; ++ks) {
        int ko = ks * 32 + quad * 8;
        bf0[ks] = *(const s16x8*)&Wt[(w * 32 + m) * Cn + ko];
        bf1[ks] = *(const s16x8*)&Wt[(w * 32 + 16 + m) * Cn + ko];
    }
    __syncthreads();

    f32x4 acc[2][2];
#pragma unroll
    for (int rt = 0; rt < 2; ++rt)
#pragma unroll
        for (int ct = 0; ct < 2; ++ct) acc[rt][ct] = (f32x4){0.f, 0.f, 0.f, 0.f};
#pragma unroll
    for (int ks = 0; ks < 4; ++ks) {
        int ko = ks * 32 + quad * 8;
        s16x8 a0 = *(const s16x8*)&sSb[(0 * 16 + m) * PAD + ko];
        s16x8 a1 = *(const s16x8*)&sSb[(1 * 16 + m) * PAD + ko];
        acc[0][0] = __builtin_amdgcn_mfma_f32_16x16x32_bf16(a0, bf0[ks], acc[0][0], 0, 0, 0);
        acc[0][1] = __builtin_amdgcn_mfma_f32_16x16x32_bf16(a0, bf1[ks], acc[0][1], 0, 0, 0);
        acc[1][0] = __builtin_amdgcn_mfma_f32_16x16x32_bf16(a1, bf0[ks], acc[1][0], 0, 0, 0);
        acc[1][1] = __builtin_amdgcn_mfma_f32_16x16x32_bf16(a1, bf1[ks], acc[1][1], 0, 0, 0);
    }

#pragma unroll
    for (int rt = 0; rt < 2; ++rt)
#pragma unroll
        for (int ct = 0; ct < 2; ++ct) {
            int col = w * 32 + ct * 16 + m;
            float bias = bc[col];
#pragma unroll
            for (int reg = 0; reg < 4; ++reg) {
                int row = rt * 16 + quad * 4 + reg;
                int node = snode[row];
                if (node >= 0)
                    h2[((size_t)b * Nn + node) * Cn + col] = fmaxf(acc[rt][ct][reg] + bias, 0.f);
            }
        }
}

// ================= K5: conv 3, frontier-restricted (tile-major) =================
__global__ __launch_bounds__(256, 4) void k_conv3L(const float* __restrict__ h2,
                                                   float* __restrict__ h3,
                                                   const unsigned short* __restrict__ Wt,
                                                   const float* __restrict__ bc,
                                                   const int* __restrict__ offs,
                                                   const int* __restrict__ ssrc,
                                                   const int* __restrict__ L3,
                                                   const int* __restrict__ meta) {
    int bidx = blockIdx.x;
    int tile = bidx >> 6, b = bidx & 63;
    int cnt3 = meta[2];
    if (tile * 32 >= cnt3) return;
    __shared__ unsigned short sSb[32 * PAD];  // 8.7 KB
    __shared__ int sIdx[32][64];              // 8 KB
    __shared__ int snode[32], slo[32], scnt[32];
    int tid = threadIdx.x;
    if (tid < 32) {
        int ti = tile * 32 + tid;
        int node = (ti < cnt3) ? L3[ti] : -1;
        snode[tid] = node;
        int lo = (node >= 0) ? offs[node] : 0;
        int hi = (node >= 0) ? offs[node + 1] : 0;
        slo[tid] = lo; scnt[tid] = hi - lo;
    }
    __syncthreads();
    int w = tid >> 6, lane = tid & 63;
#pragma unroll
    for (int r = 0; r < 8; ++r) {
        int row = w * 8 + r;
        int cnt = scnt[row];
        if (lane < cnt && lane < 64) sIdx[row][lane] = ssrc[slo[row] + lane];
    }
    __syncthreads();

    int c4 = tid & 31, u = tid >> 5;          // 4 ch per thread, rows u*4..u*4+3
    const float4* hb4 = (const float4*)(h2 + (size_t)b * (Nn * Cn));
#pragma unroll
    for (int t0 = 0; t0 < 4; ++t0) {
        int row = u * 4 + t0;
        int cnt = scnt[row], lo = slo[row];
        float4 a = {0.f, 0.f, 0.f, 0.f};
        int jm = cnt < 64 ? cnt : 64;
        for (int j = 0; j < jm; ++j) {
            float4 v = hb4[sIdx[row][j] * 32 + c4];
            a.x += v.x; a.y += v.y; a.z += v.z; a.w += v.w;
        }
        for (int j = 64; j < cnt; ++j) {      // rare overflow tail
            float4 v = hb4[ssrc[lo + j] * 32 + c4];
            a.x += v.x; a.y += v.y; a.z += v.z; a.w += v.w;
        }
        uint2 pk;
        pk.x = f2bf(a.x) | (f2bf(a.y) << 16);
        pk.y = f2bf(a.z) | (f2bf(a.w) << 16);
        *(uint2*)&sSb[row * PAD + c4 * 4] = pk;
    }

    int m = lane & 15, quad = lane >> 4;
    s16x8 bf0[4], bf1[4];
#pragma unroll
    for (int ks = 0; ks < 4; ++ks) {
        int ko = ks * 32 + quad * 8;
        bf0[ks] = *(const s16x8*)&Wt[(w * 32 + m) * Cn + ko];
        bf1[ks] = *(const s16x8*)&Wt[(w * 32 + 16 + m) * Cn + ko];
    }
    __syncthreads();

    f32x4 acc[2][2];
#pragma unroll
    for (int rt = 0; rt < 2; ++rt)
#pragma unroll
        for (int ct = 0; ct < 2; ++ct) acc[rt][ct] = (f32x4){0.f, 0.f, 0.f, 0.f};
#pragma unroll
    for (int ks = 0; ks < 4; ++ks) {
        int ko = ks * 32 + quad * 8;
        s16x8 a0 = *(const s16x8*)&sSb[(0 * 16 + m) * PAD + ko];
        s16x8 a1 = *(const s16x8*)&sSb[(1 * 16 + m) * PAD + ko];
        acc[0][0] = __builtin_amdgcn_mfma_f32_16x16x32_bf16(a0, bf0[ks], acc[0][0], 0, 0, 0);
        acc[0][1] = __builtin_amdgcn_mfma_f32_16x16x32_bf16(a0, bf1[ks], acc[0][1], 0, 0, 0);
        acc[1][0] = __builtin_amdgcn_mfma_f32_16x16x32_bf16(a1, bf0[ks], acc[1][0], 0, 0, 0);
        acc[1][1] = __builtin_amdgcn_mfma_f32_16x16x32_bf16(a1, bf1[ks], acc[1][1], 0, 0, 0);
    }

#pragma unroll
    for (int rt = 0; rt < 2; ++rt)
#pragma unroll
        for (int ct = 0; ct < 2; ++ct) {
            int col = w * 32 + ct * 16 + m;
            float bias = bc[col];
#pragma unroll
            for (int reg = 0; reg < 4; ++reg) {
                int row = rt * 16 + quad * 4 + reg;
                int node = snode[row];
                if (node >= 0)
                    h3[((size_t)b * Nn + node) * Cn + col] = fmaxf(acc[rt][ct][reg] + bias, 0.f);
            }
        }
}

// ================= K6: conv 4 (node 0 only) + classifier, fp32 exact =================
__global__ __launch_bounds__(256) void k_conv4cls(const float* __restrict__ h3,
                                                  const float* __restrict__ Wc,
                                                  const float* __restrict__ bc,
                                                  const float* __restrict__ Wcls,
                                                  const float* __restrict__ bcls,
                                                  const int* __restrict__ offs,
                                                  const int* __restrict__ ssrc,
                                                  float* __restrict__ out) {
    __shared__ float sAgg[8][Cn];   // 4 KB
    __shared__ float sred[256];
    __shared__ int sI[256];
    int b = blockIdx.x, tid = threadIdx.x;
    int e1 = offs[1];
    int lim = e1 < 256 ? e1 : 256;
    if (tid < lim) sI[tid] = ssrc[tid];
    __syncthreads();
    int c4 = tid & 31, u = tid >> 5;
    const float4* hb4 = (const float4*)(h3 + (size_t)b * (Nn * Cn));
    float4 a = {0.f, 0.f, 0.f, 0.f};
    for (int j = u; j < lim; j += 8) {
        float4 v = hb4[sI[j] * 32 + c4];
        a.x += v.x; a.y += v.y; a.z += v.z; a.w += v.w;
    }
    for (int j = 256 + u; j < e1; j += 8) {   // rare overflow tail
        float4 v = hb4[ssrc[j] * 32 + c4];
        a.x += v.x; a.y += v.y; a.z += v.z; a.w += v.w;
    }
    *(float4*)&sAgg[u][c4 * 4] = a;
    __syncthreads();
    int c = tid & 127, half = tid >> 7;
    if (tid < 128) {
        float s = sAgg[0][c];
#pragma unroll
        for (int q = 1; q < 8; ++q) s += sAgg[q][c];
        sAgg[0][c] = s;
    }
    __syncthreads();
    float s = 0.f;
    int k0 = half * 64;
#pragma unroll 8
    for (int k = k0; k < k0 + 64; ++k) s += sAgg[0][k] * Wc[k * Cn + c];
    sred[tid] = s;
    __syncthreads();
    if (tid < 128) {
        float val = fmaxf(sred[c] + sred[128 + c] + bc[c], 0.f);
        sred[tid] = val * Wcls[c];
    }
    __syncthreads();
    for (int st = 64; st > 0; st >>= 1) {
        if (tid < st) sred[tid] += sred[tid + st];
        __syncthreads();
    }
    if (tid == 0) out[b] = sred[0] + bcls[0];
}

extern "C" void kernel_launch(void* const* d_in, const int* in_sizes, int n_in,
                              void* d_out, int out_size, void* d_ws, size_t ws_size,
                              hipStream_t stream) {
    const float* x    = (const float*)d_in[0];
    const int*   ei32 = (const int*)d_in[1];
    const float* We   = (const float*)d_in[2];
    const float* be   = (const float*)d_in[3];
    const float* Wc   = (const float*)d_in[4];
    const float* bc   = (const float*)d_in[5];
    const float* Wcls = (const float*)d_in[6];
    const float* bcls = (const float*)d_in[7];
    float* out = (float*)d_out;

    // ---- workspace layout ----
    // 0        g        32768
    // 32768    meta      4096   (meta[1]=int32-detect; meta[2]=|F3|; meta[3]=|F2|)
    // 36864    offs      8192
    // 45056    ssrc     65536
    // 110592   edeg     65536
    // 176128   L3        4096
    // 180224   L2        4096
    // 184320   Wt       32768
    // 217088   pws     131072
    // 348160   indeg     4096
    // 352256   rankcnt   4096
    // 356352   h2f   33554432
    // 33910784 h3f   33554432
    char* ws = (char*)d_ws;
    float*          g       = (float*)(ws + 0);
    int*            meta    = (int*)(ws + 32768);
    int*            offs    = (int*)(ws + 36864);
    int*            ssrc    = (int*)(ws + 45056);
    float*          edeg    = (float*)(ws + 110592);
    int*            L3      = (int*)(ws + 176128);
    int*            L2      = (int*)(ws + 180224);
    unsigned short* Wt      = (unsigned short*)(ws + 184320);
    float*          pws     = (float*)(ws + 217088);
    int*            indeg   = (int*)(ws + 348160);
    int*            rankcnt = (int*)(ws + 352256);
    float*          h2f     = (float*)(ws + 356352);
    float*          h3f     = (float*)(ws + 33910784);

    k_prep<<<385, 256, 0, stream>>>(ei32, Wc, x, We, meta, Wt, pws, indeg, rankcnt);
    k_mid<<<129, 256, 0, stream>>>(ei32, pws, be, Wc, meta, indeg, L2, L3, g);
    k_scatter<<<64, 256, 0, stream>>>(ei32, meta, indeg, rankcnt, offs, ssrc, edeg);
    k_conv2L<<<32 * Bn, 256, 0, stream>>>(g, h2f, Wt, bc, offs, edeg, L2, meta);
    k_conv3L<<<32 * Bn, 256, 0, stream>>>(h2f, h3f, Wt, bc, offs, ssrc, L3, meta);
    k_conv4cls<<<Bn, 256, 0, stream>>>(h3f, Wc, bc, Wcls, bcls, offs, ssrc, out);
}

// Round 13
// 150.591 us; speedup vs baseline: 1.1008x; 1.1008x over previous
//
#include <hip/hip_runtime.h>
#include <cstdint>
#include <cstddef>

constexpr int Bn = 64;     // batch
constexpr int Nn = 1024;   // nodes per graph
constexpr int Dn = 1024;   // input feature dim
constexpr int Cn = 128;    // hidden channels
constexpr int En = 16384;  // edges per graph
constexpr int PAD = 136;   // LDS row stride in bf16 elems

typedef short s16x8 __attribute__((ext_vector_type(8)));   // 8 bf16 = 4 VGPR (MFMA A/B frag)
typedef float f32x4 __attribute__((ext_vector_type(4)));   // MFMA C/D frag

__device__ __forceinline__ uint32_t f2bf(float f) {        // fp32 -> bf16 bits, RNE
    uint32_t u = __float_as_uint(f);
    return (u + 0x7fffu + ((u >> 16) & 1u)) >> 16;
}

// ================= K1: detect | Wc->bf16^T | embedA | zero(indeg,rankcnt) =================
// blocks 0..63 detect; 64..127 wconv; 128..383 embedA; 384 zero.
// meta[1]==1 iff int32 edge data (ws poisoned 0xAA; all writers store 1 -> benign race).
__global__ __launch_bounds__(256) void k_prep(const int* __restrict__ ei32,
                                              const float* __restrict__ Wc,
                                              const float* __restrict__ x,
                                              const float* __restrict__ We,
                                              int* __restrict__ meta,
                                              unsigned short* __restrict__ Wt,
                                              float* __restrict__ pws,
                                              int* __restrict__ indeg,
                                              int* __restrict__ rankcnt) {
    int bid = blockIdx.x, tid = threadIdx.x;
    if (bid < 64) {
        __shared__ int sh;
        if (tid == 0) sh = 0;
        __syncthreads();
        int i = bid * 256 + tid;                 // [0, 16384)
        if (ei32[2 * i + 1]) atomicOr(&sh, 1);
        __syncthreads();
        if (tid == 0 && sh) meta[1] = 1;
    } else if (bid < 128) {
        int i = (bid - 64) * 256 + tid;          // [0, 16384)
        int n = i >> 7, k = i & 127;
        Wt[i] = (unsigned short)f2bf(Wc[k * Cn + n]);
    } else if (bid < 384) {
        __shared__ float sx[256];
        __shared__ float sp[256];
        int bq = bid - 128;
        int b = bq >> 2, q = bq & 3;
        int c = tid & 127, h2 = tid >> 7;
        sx[tid] = x[b * Dn + q * 256 + tid];
        __syncthreads();
        float acc = 0.f;
        int d0 = q * 256 + h2 * 128, dl = h2 * 128;
#pragma unroll 8
        for (int i = 0; i < 128; ++i) acc += sx[dl + i] * We[(d0 + i) * Cn + c];
        sp[h2 * 128 + c] = acc;
        __syncthreads();
        if (h2 == 0) pws[(b * 4 + q) * Cn + c] = sp[c] + sp[128 + c];
    } else {
        int i = tid * 4;
        indeg[i] = 0; indeg[i + 1] = 0; indeg[i + 2] = 0; indeg[i + 3] = 0;
        rankcnt[i] = 0; rankcnt[i + 1] = 0; rankcnt[i + 2] = 0; rankcnt[i + 3] = 0;
    }
}

// ================= K2: hist (0..63) | g (64..127) | levels (128) =================
// levels works on the RAW edge list (no CSR needed): F3={src:dst==0}, F2={src:dst in F3}.
// levels-block loads are 8-edge batched: 16 independent loads in flight per iteration
// (R12 post-mortem: the un-batched loop was a 48 us serial latency chain).
__global__ __launch_bounds__(256) void k_mid(const int* __restrict__ ei32,
                                             const float* __restrict__ pws,
                                             const float* __restrict__ be,
                                             const float* __restrict__ Wc,
                                             int* __restrict__ meta,
                                             int* __restrict__ indeg,
                                             int* __restrict__ L2,
                                             int* __restrict__ L3,
                                             float* __restrict__ g) {
    int bid = blockIdx.x, tid = threadIdx.x;
    if (bid < 64) {
        bool i64 = (meta[1] != 1);
        int e = bid * 256 + tid;
        int dst = ei32[i64 ? 2 * (En + e) : (En + e)] & (Nn - 1);
        atomicAdd(&indeg[dst], 1);
    } else if (bid < 128) {
        __shared__ float se[Cn];
        int b = bid - 64, c = tid & 127;
        float e = pws[(b * 4 + 0) * Cn + c] + pws[(b * 4 + 1) * Cn + c] +
                  pws[(b * 4 + 2) * Cn + c] + pws[(b * 4 + 3) * Cn + c] + be[c];
        se[c] = fmaxf(e, 0.f);                   // both tid-halves write identical value
        __syncthreads();
        float ga = 0.f;
#pragma unroll 8
        for (int k = 0; k < Cn; ++k) ga += se[k] * Wc[k * Cn + c];
        if (tid < 128) g[b * Cn + c] = ga;
    } else {
        __shared__ int f3[Nn];
        __shared__ int f2[Nn];
        __shared__ int c3s, c2s;
        for (int n = tid; n < Nn; n += 256) { f3[n] = 0; f2[n] = 0; }
        if (tid == 0) { c3s = 0; c2s = 0; }
        __syncthreads();
        bool i64 = (meta[1] != 1);
        // pass 1: F3 = {src : dst==0}; 8 edges/thread/iter -> 16 loads in flight
        for (int e0 = tid * 8; e0 < En; e0 += 2048) {
            int d[8], s[8];
#pragma unroll
            for (int j = 0; j < 8; ++j) {
                int e = e0 + j;
                d[j] = ei32[i64 ? 2 * (En + e) : (En + e)] & (Nn - 1);
                s[j] = ei32[i64 ? 2 * e : e] & (Nn - 1);
            }
#pragma unroll
            for (int j = 0; j < 8; ++j) if (d[j] == 0) f3[s[j]] = 1;
        }
        __syncthreads();
        // pass 2: F2 = {src : dst in F3}
        for (int e0 = tid * 8; e0 < En; e0 += 2048) {
            int d[8], s[8];
#pragma unroll
            for (int j = 0; j < 8; ++j) {
                int e = e0 + j;
                d[j] = ei32[i64 ? 2 * (En + e) : (En + e)] & (Nn - 1);
                s[j] = ei32[i64 ? 2 * e : e] & (Nn - 1);
            }
#pragma unroll
            for (int j = 0; j < 8; ++j) if (f3[d[j]]) f2[s[j]] = 1;
        }
        __syncthreads();
        for (int n = tid; n < Nn; n += 256) {
            if (f3[n]) L3[atomicAdd(&c3s, 1)] = n;
            if (f2[n]) L2[atomicAdd(&c2s, 1)] = n;
        }
        __syncthreads();
        if (tid == 0) { meta[2] = c3s; meta[3] = c2s; }
    }
}

// ================= K3: scatter (64 blocks; per-block redundant LDS scan; global rank atomics) =================
// pos = excl_offs[dst] + atomicAdd(&rankcnt[dst],1). Block 0 also publishes offs[] for the convs.
__global__ __launch_bounds__(256) void k_scatter(const int* __restrict__ ei32,
                                                 const int* __restrict__ meta,
                                                 const int* __restrict__ indeg,
                                                 int* __restrict__ rankcnt,
                                                 int* __restrict__ offs,
                                                 int* __restrict__ ssrc,
                                                 float* __restrict__ edeg) {
    __shared__ int sraw[Nn];
    __shared__ int sexcl[Nn];
    __shared__ int sp[256];
    int bid = blockIdx.x, tid = threadIdx.x;
    int i0 = tid * 4;
    int a0 = indeg[i0], a1 = indeg[i0 + 1], a2 = indeg[i0 + 2], a3 = indeg[i0 + 3];
    int s3 = a0 + a1 + a2 + a3;
    sraw[i0] = a0; sraw[i0 + 1] = a1; sraw[i0 + 2] = a2; sraw[i0 + 3] = a3;
    sp[tid] = s3;
    __syncthreads();
    for (int off = 1; off < 256; off <<= 1) {
        int add = (tid >= off) ? sp[tid - off] : 0;
        __syncthreads();
        sp[tid] += add;
        __syncthreads();
    }
    int excl = sp[tid] - s3;
    sexcl[i0] = excl;
    sexcl[i0 + 1] = excl + a0;
    sexcl[i0 + 2] = excl + a0 + a1;
    sexcl[i0 + 3] = excl + a0 + a1 + a2;
    if (bid == 0) {
        offs[i0 + 1] = excl + a0;
        offs[i0 + 2] = excl + a0 + a1;
        offs[i0 + 3] = excl + a0 + a1 + a2;
        offs[i0 + 4] = excl + s3;
        if (tid == 0) offs[0] = 0;
    }
    __syncthreads();
    bool i64 = (meta[1] != 1);
    int e = bid * 256 + tid;
    int src = ei32[i64 ? 2 * e : e] & (Nn - 1);
    int dst = ei32[i64 ? 2 * (En + e) : (En + e)] & (Nn - 1);
    int rank = atomicAdd(&rankcnt[dst], 1);
    int pos = sexcl[dst] + rank;
    if (pos >= 0 && pos < En) { ssrc[pos] = src; edeg[pos] = (float)sraw[src]; }
}

// ================= K4: conv 1+2 fused, frontier-restricted (tile-major: XCD = b%8) =================
__global__ __launch_bounds__(256, 4) void k_conv2L(const float* __restrict__ g,
                                                   float* __restrict__ h2,
                                                   const unsigned short* __restrict__ Wt,
                                                   const float* __restrict__ bc,
                                                   const int* __restrict__ offs,
                                                   const float* __restrict__ edeg,
                                                   const int* __restrict__ L2,
                                                   const int* __restrict__ meta) {
    int bidx = blockIdx.x;
    int tile = bidx >> 6, b = bidx & 63;
    int cnt2 = meta[3];
    if (tile * 32 >= cnt2) return;
    __shared__ unsigned short sSb[32 * PAD];  // 8.7 KB
    __shared__ float sEd[32][64];             // 8 KB
    __shared__ int snode[32], slo[32], scnt[32];
    int tid = threadIdx.x;
    if (tid < 32) {
        int ti = tile * 32 + tid;
        int node = (ti < cnt2) ? L2[ti] : -1;
        snode[tid] = node;
        int lo = (node >= 0) ? offs[node] : 0;
        int hi = (node >= 0) ? offs[node + 1] : 0;
        slo[tid] = lo; scnt[tid] = hi - lo;
    }
    __syncthreads();
    int w = tid >> 6, lane = tid & 63;
#pragma unroll
    for (int r = 0; r < 8; ++r) {
        int row = w * 8 + r;
        int cnt = scnt[row];
        if (lane < cnt && lane < 64) sEd[row][lane] = edeg[slo[row] + lane];
    }
    __syncthreads();

    int c2 = tid & 63;
    float gx = g[b * Cn + 2 * c2], gy = g[b * Cn + 2 * c2 + 1];
    float bx = bc[2 * c2], by = bc[2 * c2 + 1];
#pragma unroll
    for (int t0 = 0; t0 < 8; ++t0) {
        int row = w * 8 + t0;
        int cnt = scnt[row], lo = slo[row];
        float s0 = 0.f, s1 = 0.f;
        int jm = cnt < 64 ? cnt : 64;
        for (int j = 0; j < jm; ++j) {
            float d = sEd[row][j];
            s0 += fmaxf(fmaf(d, gx, bx), 0.f);
            s1 += fmaxf(fmaf(d, gy, by), 0.f);
        }
        for (int j = 64; j < cnt; ++j) {      // rare overflow tail
            float d = edeg[lo + j];
            s0 += fmaxf(fmaf(d, gx, bx), 0.f);
            s1 += fmaxf(fmaf(d, gy, by), 0.f);
        }
        *(uint32_t*)&sSb[row * PAD + 2 * c2] = f2bf(s0) | (f2bf(s1) << 16);
    }

    int m = lane & 15, quad = lane >> 4;
    s16x8 bf0[4], bf1[4];
#pragma unroll
    for (int ks = 0; ks < 4; ++ks) {
        int ko = ks * 32 + quad * 8;
        bf0[ks] = *(const s16x8*)&Wt[(w * 32 + m) * Cn + ko];
        bf1[ks] = *(const s16x8*)&Wt[(w * 32 + 16 + m) * Cn + ko];
    }
    __syncthreads();

    f32x4 acc[2][2];
#pragma unroll
    for (int rt = 0; rt < 2; ++rt)
#pragma unroll
        for (int ct = 0; ct < 2; ++ct) acc[rt][ct] = (f32x4){0.f, 0.f, 0.f, 0.f};
#pragma unroll
    for (int ks = 0; ks < 4; ++ks) {
        int ko = ks * 32 + quad * 8;
        s16x8 a0 = *(const s16x8*)&sSb[(0 * 16 + m) * PAD + ko];
        s16x8 a1 = *(const s16x8*)&sSb[(1 * 16 + m) * PAD + ko];
        acc[0][0] = __builtin_amdgcn_mfma_f32_16x16x32_bf16(a0, bf0[ks], acc[0][0], 0, 0, 0);
        acc[0][1] = __builtin_amdgcn_mfma_f32_16x16x32_bf16(a0, bf1[ks], acc[0][1], 0, 0, 0);
        acc[1][0] = __builtin_amdgcn_mfma_f32_16x16x32_bf16(a1, bf0[ks], acc[1][0], 0, 0, 0);
        acc[1][1] = __builtin_amdgcn_mfma_f32_16x16x32_bf16(a1, bf1[ks], acc[1][1], 0, 0, 0);
    }

#pragma unroll
    for (int rt = 0; rt < 2; ++rt)
#pragma unroll
        for (int ct = 0; ct < 2; ++ct) {
            int col = w * 32 + ct * 16 + m;
            float bias = bc[col];
#pragma unroll
            for (int reg = 0; reg < 4; ++reg) {
                int row = rt * 16 + quad * 4 + reg;
                int node = snode[row];
                if (node >= 0)
                    h2[((size_t)b * Nn + node) * Cn + col] = fmaxf(acc[rt][ct][reg] + bias, 0.f);
            }
        }
}

// ================= K5: conv 3, frontier-restricted (tile-major) =================
__global__ __launch_bounds__(256, 4) void k_conv3L(const float* __restrict__ h2,
                                                   float* __restrict__ h3,
                                                   const unsigned short* __restrict__ Wt,
                                                   const float* __restrict__ bc,
                                                   const int* __restrict__ offs,
                                                   const int* __restrict__ ssrc,
                                                   const int* __restrict__ L3,
                                                   const int* __restrict__ meta) {
    int bidx = blockIdx.x;
    int tile = bidx >> 6, b = bidx & 63;
    int cnt3 = meta[2];
    if (tile * 32 >= cnt3) return;
    __shared__ unsigned short sSb[32 * PAD];  // 8.7 KB
    __shared__ int sIdx[32][64];              // 8 KB
    __shared__ int snode[32], slo[32], scnt[32];
    int tid = threadIdx.x;
    if (tid < 32) {
        int ti = tile * 32 + tid;
        int node = (ti < cnt3) ? L3[ti] : -1;
        snode[tid] = node;
        int lo = (node >= 0) ? offs[node] : 0;
        int hi = (node >= 0) ? offs[node + 1] : 0;
        slo[tid] = lo; scnt[tid] = hi - lo;
    }
    __syncthreads();
    int w = tid >> 6, lane = tid & 63;
#pragma unroll
    for (int r = 0; r < 8; ++r) {
        int row = w * 8 + r;
        int cnt = scnt[row];
        if (lane < cnt && lane < 64) sIdx[row][lane] = ssrc[slo[row] + lane];
    }
    __syncthreads();

    int c4 = tid & 31, u = tid >> 5;          // 4 ch per thread, rows u*4..u*4+3
    const float4* hb4 = (const float4*)(h2 + (size_t)b * (Nn * Cn));
#pragma unroll
    for (int t0 = 0; t0 < 4; ++t0) {
        int row = u * 4 + t0;
        int cnt = scnt[row], lo = slo[row];
        float4 a = {0.f, 0.f, 0.f, 0.f};
        int jm = cnt < 64 ? cnt : 64;
        for (int j = 0; j < jm; ++j) {
            float4 v = hb4[sIdx[row][j] * 32 + c4];
            a.x += v.x; a.y += v.y; a.z += v.z; a.w += v.w;
        }
        for (int j = 64; j < cnt; ++j) {      // rare overflow tail
            float4 v = hb4[ssrc[lo + j] * 32 + c4];
            a.x += v.x; a.y += v.y; a.z += v.z; a.w += v.w;
        }
        uint2 pk;
        pk.x = f2bf(a.x) | (f2bf(a.y) << 16);
        pk.y = f2bf(a.z) | (f2bf(a.w) << 16);
        *(uint2*)&sSb[row * PAD + c4 * 4] = pk;
    }

    int m = lane & 15, quad = lane >> 4;
    s16x8 bf0[4], bf1[4];
#pragma unroll
    for (int ks = 0; ks < 4; ++ks) {
        int ko = ks * 32 + quad * 8;
        bf0[ks] = *(const s16x8*)&Wt[(w * 32 + m) * Cn + ko];
        bf1[ks] = *(const s16x8*)&Wt[(w * 32 + 16 + m) * Cn + ko];
    }
    __syncthreads();

    f32x4 acc[2][2];
#pragma unroll
    for (int rt = 0; rt < 2; ++rt)
#pragma unroll
        for (int ct = 0; ct < 2; ++ct) acc[rt][ct] = (f32x4){0.f, 0.f, 0.f, 0.f};
#pragma unroll
    for (int ks = 0; ks < 4; ++ks) {
        int ko = ks * 32 + quad * 8;
        s16x8 a0 = *(const s16x8*)&sSb[(0 * 16 + m) * PAD + ko];
        s16x8 a1 = *(const s16x8*)&sSb[(1 * 16 + m) * PAD + ko];
        acc[0][0] = __builtin_amdgcn_mfma_f32_16x16x32_bf16(a0, bf0[ks], acc[0][0], 0, 0, 0);
        acc[0][1] = __builtin_amdgcn_mfma_f32_16x16x32_bf16(a0, bf1[ks], acc[0][1], 0, 0, 0);
        acc[1][0] = __builtin_amdgcn_mfma_f32_16x16x32_bf16(a1, bf0[ks], acc[1][0], 0, 0, 0);
        acc[1][1] = __builtin_amdgcn_mfma_f32_16x16x32_bf16(a1, bf1[ks], acc[1][1], 0, 0, 0);
    }

#pragma unroll
    for (int rt = 0; rt < 2; ++rt)
#pragma unroll
        for (int ct = 0; ct < 2; ++ct) {
            int col = w * 32 + ct * 16 + m;
            float bias = bc[col];
#pragma unroll
            for (int reg = 0; reg < 4; ++reg) {
                int row = rt * 16 + quad * 4 + reg;
                int node = snode[row];
                if (node >= 0)
                    h3[((size_t)b * Nn + node) * Cn + col] = fmaxf(acc[rt][ct][reg] + bias, 0.f);
            }
        }
}

// ================= K6: conv 4 (node 0 only) + classifier, fp32 exact =================
__global__ __launch_bounds__(256) void k_conv4cls(const float* __restrict__ h3,
                                                  const float* __restrict__ Wc,
                                                  const float* __restrict__ bc,
                                                  const float* __restrict__ Wcls,
                                                  const float* __restrict__ bcls,
                                                  const int* __restrict__ offs,
                                                  const int* __restrict__ ssrc,
                                                  float* __restrict__ out) {
    __shared__ float sAgg[8][Cn];   // 4 KB
    __shared__ float sred[256];
    __shared__ int sI[256];
    int b = blockIdx.x, tid = threadIdx.x;
    int e1 = offs[1];
    int lim = e1 < 256 ? e1 : 256;
    if (tid < lim) sI[tid] = ssrc[tid];
    __syncthreads();
    int c4 = tid & 31, u = tid >> 5;
    const float4* hb4 = (const float4*)(h3 + (size_t)b * (Nn * Cn));
    float4 a = {0.f, 0.f, 0.f, 0.f};
    for (int j = u; j < lim; j += 8) {
        float4 v = hb4[sI[j] * 32 + c4];
        a.x += v.x; a.y += v.y; a.z += v.z; a.w += v.w;
    }
    for (int j = 256 + u; j < e1; j += 8) {   // rare overflow tail
        float4 v = hb4[ssrc[j] * 32 + c4];
        a.x += v.x; a.y += v.y; a.z += v.z; a.w += v.w;
    }
    *(float4*)&sAgg[u][c4 * 4] = a;
    __syncthreads();
    int c = tid & 127, half = tid >> 7;
    if (tid < 128) {
        float s = sAgg[0][c];
#pragma unroll
        for (int q = 1; q < 8; ++q) s += sAgg[q][c];
        sAgg[0][c] = s;
    }
    __syncthreads();
    float s = 0.f;
    int k0 = half * 64;
#pragma unroll 8
    for (int k = k0; k < k0 + 64; ++k) s += sAgg[0][k] * Wc[k * Cn + c];
    sred[tid] = s;
    __syncthreads();
    if (tid < 128) {
        float val = fmaxf(sred[c] + sred[128 + c] + bc[c], 0.f);
        sred[tid] = val * Wcls[c];
    }
    __syncthreads();
    for (int st = 64; st > 0; st >>= 1) {
        if (tid < st) sred[tid] += sred[tid + st];
        __syncthreads();
    }
    if (tid == 0) out[b] = sred[0] + bcls[0];
}

extern "C" void kernel_launch(void* const* d_in, const int* in_sizes, int n_in,
                              void* d_out, int out_size, void* d_ws, size_t ws_size,
                              hipStream_t stream) {
    const float* x    = (const float*)d_in[0];
    const int*   ei32 = (const int*)d_in[1];
    const float* We   = (const float*)d_in[2];
    const float* be   = (const float*)d_in[3];
    const float* Wc   = (const float*)d_in[4];
    const float* bc   = (const float*)d_in[5];
    const float* Wcls = (const float*)d_in[6];
    const float* bcls = (const float*)d_in[7];
    float* out = (float*)d_out;

    // ---- workspace layout ----
    // 0        g        32768
    // 32768    meta      4096   (meta[1]=int32-detect; meta[2]=|F3|; meta[3]=|F2|)
    // 36864    offs      8192
    // 45056    ssrc     65536
    // 110592   edeg     65536
    // 176128   L3        4096
    // 180224   L2        4096
    // 184320   Wt       32768
    // 217088   pws     131072
    // 348160   indeg     4096
    // 352256   rankcnt   4096
    // 356352   h2f   33554432
    // 33910784 h3f   33554432
    char* ws = (char*)d_ws;
    float*          g       = (float*)(ws + 0);
    int*            meta    = (int*)(ws + 32768);
    int*            offs    = (int*)(ws + 36864);
    int*            ssrc    = (int*)(ws + 45056);
    float*          edeg    = (float*)(ws + 110592);
    int*            L3      = (int*)(ws + 176128);
    int*            L2      = (int*)(ws + 180224);
    unsigned short* Wt      = (unsigned short*)(ws + 184320);
    float*          pws     = (float*)(ws + 217088);
    int*            indeg   = (int*)(ws + 348160);
    int*            rankcnt = (int*)(ws + 352256);
    float*          h2f     = (float*)(ws + 356352);
    float*          h3f     = (float*)(ws + 33910784);

    k_prep<<<385, 256, 0, stream>>>(ei32, Wc, x, We, meta, Wt, pws, indeg, rankcnt);
    k_mid<<<129, 256, 0, stream>>>(ei32, pws, be, Wc, meta, indeg, L2, L3, g);
    k_scatter<<<64, 256, 0, stream>>>(ei32, meta, indeg, rankcnt, offs, ssrc, edeg);
    k_conv2L<<<32 * Bn, 256, 0, stream>>>(g, h2f, Wt, bc, offs, edeg, L2, meta);
    k_conv3L<<<32 * Bn, 256, 0, stream>>>(h2f, h3f, Wt, bc, offs, ssrc, L3, meta);
    k_conv4cls<<<Bn, 256, 0, stream>>>(h3f, Wc, bc, Wcls, bcls, offs, ssrc, out);
}